// Round 8
// baseline (52.680 us; speedup 1.0000x reference)
//
#include <hip/hip_runtime.h>
#include <hip/hip_fp16.h>

#define DIM 64

// ---------- pass 1: compress x (f32) -> xh (fp16) in workspace ----------
__global__ __launch_bounds__(256) void cvt_half_kernel(
    const float* __restrict__ x, __half* __restrict__ xh, int n4)
{
    int i = blockIdx.x * blockDim.x + threadIdx.x;
    const int stride = gridDim.x * blockDim.x;
    for (; i < n4; i += stride) {
        const float4 v = ((const float4*)x)[i];
        __half2 h0 = __floats2half2_rn(v.x, v.y);
        __half2 h1 = __floats2half2_rn(v.z, v.w);
        uint2 u;
        u.x = *(const unsigned int*)&h0;
        u.y = *(const unsigned int*)&h1;
        ((uint2*)xh)[i] = u;
    }
}

// ---------- pass 2: CSR SpMM over fp16 x ----------
// One wave per row. 8 groups x 8 lanes; group g owns edge slots k+g and
// k+8+g; lane reads 16B (8 halves) of that edge's x-row -> one dwordx4
// moves 8 edges' rows (1 KiB, 1 line per edge). Indices clamped to the
// row's own last edge (duplicate gathers hit an already-fetched line).
// FMA written element-wise as acc += (float)h * w so clang emits
// v_fma_mix_f32 (f16 x f32 + f32 in ONE instruction, no separate cvt).
__global__ __launch_bounds__(256) void spmm_half_kernel(
    const __half* __restrict__ xh,
    const int*   __restrict__ indptr,
    const int*   __restrict__ indices,
    const float* __restrict__ values,
    float*       __restrict__ out,
    int n_nodes)
{
    const int row  = (int)((blockIdx.x * blockDim.x + threadIdx.x) >> 6);
    const int lane = (int)(threadIdx.x & 63);
    if (row >= n_nodes) return;
    const int g = lane >> 3;        // edge slot 0..7
    const int t = lane & 7;         // column octet: cols [t*8, t*8+8)

    const int start = indptr[row];
    const int end   = indptr[row + 1];

    float a[8] = {0.f,0.f,0.f,0.f,0.f,0.f,0.f,0.f};

    if (start < end) {
        const int last = end - 1;
        for (int k = start; k < end; k += 16) {
            const int e0 = k + g;
            const int e1 = k + 8 + g;
            const int i0 = (e0 <= last) ? e0 : last;
            const int i1 = (e1 <= last) ? e1 : last;
            const int c0 = indices[i0];
            const int c1 = indices[i1];
            const float w0 = (e0 <= last) ? values[i0] : 0.0f;
            const float w1 = (e1 <= last) ? values[i1] : 0.0f;

            const uint4 p0 = *(const uint4*)(xh + (((unsigned)c0) << 6) + (t << 3));
            const uint4 p1 = *(const uint4*)(xh + (((unsigned)c1) << 6) + (t << 3));

            const __half* h0 = (const __half*)&p0;
            const __half* h1 = (const __half*)&p1;
#pragma unroll
            for (int j = 0; j < 8; ++j) a[j] += __half2float(h0[j]) * w0;
#pragma unroll
            for (int j = 0; j < 8; ++j) a[j] += __half2float(h1[j]) * w1;
        }
    }

    // Sum the 8 edge-groups: lanes {l^8, l^16, l^32} hold the same columns.
#define RED(m) a[0]+=__shfl_xor(a[0],m); a[1]+=__shfl_xor(a[1],m); \
               a[2]+=__shfl_xor(a[2],m); a[3]+=__shfl_xor(a[3],m); \
               a[4]+=__shfl_xor(a[4],m); a[5]+=__shfl_xor(a[5],m); \
               a[6]+=__shfl_xor(a[6],m); a[7]+=__shfl_xor(a[7],m);
    RED(8) RED(16) RED(32)
#undef RED

    if (lane < 8) {
        float4 r0; r0.x=a[0]; r0.y=a[1]; r0.z=a[2]; r0.w=a[3];
        float4 r1; r1.x=a[4]; r1.y=a[5]; r1.z=a[6]; r1.w=a[7];
        float* dst = out + (((size_t)row) << 6) + (t << 3);
        *(float4*)(dst)     = r0;
        *(float4*)(dst + 4) = r1;
    }
}

// ---------- fallback (ws too small): f32 quad kernel (round 3) ----------
__global__ __launch_bounds__(256) void spmm_quad_kernel(
    const float* __restrict__ x,
    const int*   __restrict__ indptr,
    const int*   __restrict__ indices,
    const float* __restrict__ values,
    float*       __restrict__ out,
    int n_nodes)
{
    const int row  = (int)((blockIdx.x * blockDim.x + threadIdx.x) >> 6);
    const int lane = (int)(threadIdx.x & 63);
    if (row >= n_nodes) return;

    const int start = indptr[row];
    const int end   = indptr[row + 1];
    const int g     = lane >> 4;
    const unsigned col4 = (unsigned)(lane & 15) << 2;

    float ax = 0.f, ay = 0.f, az = 0.f, aw = 0.f;

    if (start < end) {
        const int last = end - 1;
        for (int k = start; k < end; k += 16) {
            const int e0 = k +  0 + g, e1 = k + 4 + g, e2 = k + 8 + g, e3 = k + 12 + g;
            const int ce0 = e0 <= last ? e0 : last;
            const int ce1 = e1 <= last ? e1 : last;
            const int ce2 = e2 <= last ? e2 : last;
            const int ce3 = e3 <= last ? e3 : last;
            const int c0 = indices[ce0], c1 = indices[ce1];
            const int c2 = indices[ce2], c3 = indices[ce3];
            const float w0 = (e0 <= last) ? values[ce0] : 0.0f;
            const float w1 = (e1 <= last) ? values[ce1] : 0.0f;
            const float w2 = (e2 <= last) ? values[ce2] : 0.0f;
            const float w3 = (e3 <= last) ? values[ce3] : 0.0f;
            const float4 a0 = *(const float4*)(x + (((unsigned)c0) << 6) + col4);
            const float4 a1 = *(const float4*)(x + (((unsigned)c1) << 6) + col4);
            const float4 a2 = *(const float4*)(x + (((unsigned)c2) << 6) + col4);
            const float4 a3 = *(const float4*)(x + (((unsigned)c3) << 6) + col4);
            ax += w0 * a0.x; ay += w0 * a0.y; az += w0 * a0.z; aw += w0 * a0.w;
            ax += w1 * a1.x; ay += w1 * a1.y; az += w1 * a1.z; aw += w1 * a1.w;
            ax += w2 * a2.x; ay += w2 * a2.y; az += w2 * a2.z; aw += w2 * a2.w;
            ax += w3 * a3.x; ay += w3 * a3.y; az += w3 * a3.z; aw += w3 * a3.w;
        }
    }

    ax += __shfl_xor(ax, 16); ay += __shfl_xor(ay, 16);
    az += __shfl_xor(az, 16); aw += __shfl_xor(aw, 16);
    ax += __shfl_xor(ax, 32); ay += __shfl_xor(ay, 32);
    az += __shfl_xor(az, 32); aw += __shfl_xor(aw, 32);

    if (lane < 16) {
        float4 r; r.x = ax; r.y = ay; r.z = az; r.w = aw;
        *(float4*)(out + ((size_t)row << 6) + col4) = r;
    }
}

extern "C" void kernel_launch(void* const* d_in, const int* in_sizes, int n_in,
                              void* d_out, int out_size, void* d_ws, size_t ws_size,
                              hipStream_t stream) {
    const float* x       = (const float*)d_in[0];
    const int*   indptr  = (const int*)  d_in[1];
    const int*   indices = (const int*)  d_in[2];
    const float* values  = (const float*)d_in[3];
    float*       out     = (float*)d_out;

    const int n_nodes = in_sizes[1] - 1;     // indptr has N+1 entries
    const int n_xelem = in_sizes[0];         // N * 64

    const int threads = 256;
    const int rows_per_block = threads / 64;
    const int blocks = (n_nodes + rows_per_block - 1) / rows_per_block;

    const size_t needed = (size_t)n_xelem * sizeof(__half);
    if (ws_size >= needed) {
        __half* xh = (__half*)d_ws;
        const int n4 = n_xelem / 4;
        cvt_half_kernel<<<2048, 256, 0, stream>>>(x, xh, n4);
        spmm_half_kernel<<<blocks, threads, 0, stream>>>(
            xh, indptr, indices, values, out, n_nodes);
    } else {
        spmm_quad_kernel<<<blocks, threads, 0, stream>>>(
            x, indptr, indices, values, out, n_nodes);
    }
}